// Round 1
// baseline (1994.473 us; speedup 1.0000x reference)
//
#include <hip/hip_runtime.h>
#include <hip/hip_bf16.h>

#define H 128
#define NR 6
#define MLP_TILE 64
#define WP 132   // padded LDS stride for W (breaks bank conflicts, keeps float4 align)
#define HP 68    // padded LDS stride for h tile (float4-aligned)

__device__ __forceinline__ float silu_f(float v) {
    return v / (1.0f + __expf(-v));
}

// ---------------------------------------------------------------- zero h
__global__ __launch_bounds__(256) void zero_f4(float4* __restrict__ p, int n4) {
    int i = blockIdx.x * 256 + threadIdx.x;
    if (i < n4) p[i] = make_float4(0.f, 0.f, 0.f, 0.f);
}

// ------------------------------------------------- edge gather + scatter-add
// Each 32-lane group handles one edge row (128 cols as float4/lane).
// Block = 256 threads = 8 edge-slots; loops over 4 groups -> 32 edges/block.
__global__ __launch_bounds__(256) void edge_scatter(
    const float* __restrict__ x, const float* __restrict__ rbf,
    const int* __restrict__ idx, const float* __restrict__ W_rbf,
    float* __restrict__ h, int E)
{
    __shared__ float wr[NR * H];   // transposed: wr[j*H + c] = W_rbf[c][j]
    const int t = threadIdx.x;
    for (int i = t; i < NR * H; i += 256) {
        int c = i / NR, j = i - c * NR;      // W_rbf row-major [H][NR]
        wr[j * H + c] = W_rbf[i];
    }
    __syncthreads();
    const int lane = t & 31;                 // column group: 4 cols per lane
    const int sub  = t >> 5;                 // edge slot within block
    #pragma unroll
    for (int g = 0; g < 4; ++g) {
        const long long e = (long long)blockIdx.x * 32 + g * 8 + sub;
        if (e < E) {
            float rc[NR];
            #pragma unroll
            for (int j = 0; j < NR; ++j) rc[j] = rbf[e * NR + j];
            const int node = idx[e];
            const float4 xv = ((const float4*)(x + e * H))[lane];
            float4 r = make_float4(0.f, 0.f, 0.f, 0.f);
            #pragma unroll
            for (int j = 0; j < NR; ++j) {
                const float4 w = *(const float4*)&wr[j * H + lane * 4];
                r.x += rc[j] * w.x; r.y += rc[j] * w.y;
                r.z += rc[j] * w.z; r.w += rc[j] * w.w;
            }
            float* hp = h + (long long)node * H + lane * 4;
            unsafeAtomicAdd(hp + 0, r.x * xv.x);
            unsafeAtomicAdd(hp + 1, r.y * xv.y);
            unsafeAtomicAdd(hp + 2, r.z * xv.z);
            unsafeAtomicAdd(hp + 3, r.w * xv.w);
        }
    }
}

// ---------------------------------------------------------------- MLP stack
__device__ __forceinline__ void stage_W(const float* __restrict__ Wg, float* Wl, int t) {
    // global row-major W[c][k] -> LDS transposed Wl[k*WP + c]
    for (int i = t; i < H * H; i += 256) {
        int c = i >> 7, k = i & 127;
        Wl[k * WP + c] = Wg[i];
    }
}

__device__ __forceinline__ void layer_compute(const float* Wl, const float* hl,
        const float* __restrict__ bg, float (&acc)[4][8], int rg, int cg)
{
    #pragma unroll
    for (int j = 0; j < 8; ++j) {
        float b = bg ? bg[cg * 8 + j] : 0.f;
        #pragma unroll
        for (int r = 0; r < 4; ++r) acc[r][j] = b;
    }
    #pragma unroll 2
    for (int k = 0; k < H; ++k) {
        const float4 hv = *(const float4*)&hl[k * HP + rg * 4];
        const float4 wa = *(const float4*)&Wl[k * WP + cg * 8];
        const float4 wb = *(const float4*)&Wl[k * WP + cg * 8 + 4];
        const float hr[4] = {hv.x, hv.y, hv.z, hv.w};
        const float wc[8] = {wa.x, wa.y, wa.z, wa.w, wb.x, wb.y, wb.z, wb.w};
        #pragma unroll
        for (int r = 0; r < 4; ++r)
            #pragma unroll
            for (int j = 0; j < 8; ++j)
                acc[r][j] += hr[r] * wc[j];
    }
}

__device__ __forceinline__ void writeback_silu(float* hl, float (&acc)[4][8], int rg, int cg) {
    #pragma unroll
    for (int j = 0; j < 8; ++j) {
        const int c = cg * 8 + j;
        float4 v = make_float4(silu_f(acc[0][j]), silu_f(acc[1][j]),
                               silu_f(acc[2][j]), silu_f(acc[3][j]));
        *(float4*)&hl[c * HP + rg * 4] = v;
    }
}

__global__ __launch_bounds__(256) void mlp4(
    const float* __restrict__ hg,
    const float* __restrict__ W1, const float* __restrict__ b1,
    const float* __restrict__ W2, const float* __restrict__ b2,
    const float* __restrict__ W3, const float* __restrict__ b3,
    const float* __restrict__ Wo,
    float* __restrict__ out, int N)
{
    __shared__ float Wl[H * WP];      // 67.5 KB
    __shared__ float hl[H * HP];      // 34 KB  (transposed: hl[k*HP + r])
    const int t = threadIdx.x;
    const int rg = t >> 4, cg = t & 15;   // 16x16 thread grid: 4 rows x 8 cols each
    const int row0 = blockIdx.x * MLP_TILE;

    // stage h tile transposed (coalesced global read)
    for (int i = t; i < MLP_TILE * H; i += 256) {
        int r = i >> 7, k = i & 127;
        int row = row0 + r;
        hl[k * HP + r] = (row < N) ? hg[(size_t)row * H + k] : 0.f;
    }
    stage_W(W1, Wl, t);
    __syncthreads();

    float acc[4][8];
    layer_compute(Wl, hl, b1, acc, rg, cg);
    __syncthreads();
    writeback_silu(hl, acc, rg, cg);
    stage_W(W2, Wl, t);
    __syncthreads();

    layer_compute(Wl, hl, b2, acc, rg, cg);
    __syncthreads();
    writeback_silu(hl, acc, rg, cg);
    stage_W(W3, Wl, t);
    __syncthreads();

    layer_compute(Wl, hl, b3, acc, rg, cg);
    __syncthreads();
    writeback_silu(hl, acc, rg, cg);
    stage_W(Wo, Wl, t);
    __syncthreads();

    layer_compute(Wl, hl, nullptr, acc, rg, cg);

    #pragma unroll
    for (int r = 0; r < 4; ++r) {
        const int row = row0 + rg * 4 + r;
        if (row < N) {
            float4 o0 = make_float4(acc[r][0], acc[r][1], acc[r][2], acc[r][3]);
            float4 o1 = make_float4(acc[r][4], acc[r][5], acc[r][6], acc[r][7]);
            float4* op = (float4*)(out + (size_t)row * H + cg * 8);
            op[0] = o0; op[1] = o1;
        }
    }
}

// ---------------------------------------------------------------- launch
extern "C" void kernel_launch(void* const* d_in, const int* in_sizes, int n_in,
                              void* d_out, int out_size, void* d_ws, size_t ws_size,
                              hipStream_t stream) {
    const float* x     = (const float*)d_in[0];
    const float* rbf   = (const float*)d_in[1];
    const int*   idx   = (const int*)d_in[2];
    // d_in[3] = num_nodes scalar (N derived from out_size instead)
    const float* W_rbf = (const float*)d_in[4];
    const float* W1    = (const float*)d_in[5];
    const float* b1    = (const float*)d_in[6];
    const float* W2    = (const float*)d_in[7];
    const float* b2    = (const float*)d_in[8];
    const float* W3    = (const float*)d_in[9];
    const float* b3    = (const float*)d_in[10];
    const float* Wo    = (const float*)d_in[11];
    float* out = (float*)d_out;
    float* h   = (float*)d_ws;              // [N, H] fp32 accumulator, 25.6 MB

    const int E = in_sizes[0] / H;
    const int N = out_size / H;

    const int n4 = N * H / 4;
    zero_f4<<<(n4 + 255) / 256, 256, 0, stream>>>((float4*)h, n4);
    edge_scatter<<<(E + 31) / 32, 256, 0, stream>>>(x, rbf, idx, W_rbf, h, E);
    mlp4<<<(N + MLP_TILE - 1) / MLP_TILE, 256, 0, stream>>>(
        h, W1, b1, W2, b2, W3, b3, Wo, out, N);
}

// Round 2
// 961.725 us; speedup vs baseline: 2.0739x; 2.0739x over previous
//
#include <hip/hip_runtime.h>
#include <hip/hip_bf16.h>

#define H 128
#define NR 6
#define MT 128          // MLP rows per block
#define LDW 132         // padded LDS stride (16B-aligned float4 reads)

__device__ __forceinline__ float silu_f(float v) {
    return v / (1.0f + __expf(-v));
}

// ------------------------------------------------------------ histogram
__global__ __launch_bounds__(256) void hist_k(const int* __restrict__ idx,
                                              int* __restrict__ counts, int E) {
    int i = blockIdx.x * 256 + threadIdx.x;
    if (i < E) atomicAdd(&counts[idx[i]], 1);
}

// ------------------------------------------------- single-block chunked scan
__global__ __launch_bounds__(1024) void scan_k(const int* __restrict__ counts,
                                               int* __restrict__ offsets, int N) {
    __shared__ int tmp[1024];
    const int tid = threadIdx.x;
    const int CHUNK = (N + 1023) >> 10;
    const int base = tid * CHUNK;
    int s = 0;
    for (int k = 0; k < CHUNK; ++k) {
        int j = base + k;
        if (j < N) s += counts[j];
    }
    tmp[tid] = s;
    __syncthreads();
    // Hillis-Steele inclusive scan over 1024 thread-sums
    for (int off = 1; off < 1024; off <<= 1) {
        int v = (tid >= off) ? tmp[tid - off] : 0;
        __syncthreads();
        tmp[tid] += v;
        __syncthreads();
    }
    int run = tmp[tid] - s;   // exclusive prefix of this thread's chunk
    for (int k = 0; k < CHUNK; ++k) {
        int j = base + k;
        if (j < N) { offsets[j] = run; run += counts[j]; }
    }
    if (tid == 1023) offsets[N] = run;   // total (last chunks are past N, s=0)
}

// ------------------------------------------------------------ CSR fill
__global__ __launch_bounds__(256) void fill_k(const int* __restrict__ idx,
                                              const int* __restrict__ offsets,
                                              int* __restrict__ cursor,
                                              int* __restrict__ elist, int E) {
    int i = blockIdx.x * 256 + threadIdx.x;
    if (i < E) {
        int node = idx[i];
        int pos = atomicAdd(&cursor[node], 1);
        elist[offsets[node] + pos] = i;
    }
}

// ---------------------------------------------- gather: one wave per node
// lane handles cols {2*lane, 2*lane+1}; h row written exactly once.
__global__ __launch_bounds__(256) void gather_k(
    const float* __restrict__ x, const float* __restrict__ rbf,
    const float* __restrict__ W_rbf,
    const int* __restrict__ offsets, const int* __restrict__ elist,
    float* __restrict__ h, int N)
{
    const int t = threadIdx.x;
    const int lane = t & 63;
    const int node = blockIdx.x * 4 + (t >> 6);
    if (node >= N) return;

    // W_rbf rows for this lane's two columns: 12 consecutive floats
    const float4* wp = (const float4*)(W_rbf + lane * 12);
    const float4 wa = wp[0], wb = wp[1], wc = wp[2];
    const float wr0[NR] = {wa.x, wa.y, wa.z, wa.w, wb.x, wb.y};
    const float wr1[NR] = {wb.z, wb.w, wc.x, wc.y, wc.z, wc.w};

    const int beg = offsets[node], end = offsets[node + 1];
    float ax = 0.f, ay = 0.f;

    int p = beg;
    for (; p + 1 < end; p += 2) {
        const int e0 = elist[p], e1 = elist[p + 1];
        const float2 xv0 = *(const float2*)(x + (size_t)e0 * H + lane * 2);
        const float2 xv1 = *(const float2*)(x + (size_t)e1 * H + lane * 2);
        const float* r0 = rbf + (size_t)e0 * NR;
        const float* r1 = rbf + (size_t)e1 * NR;
        float m0 = 0.f, m1 = 0.f, n0 = 0.f, n1 = 0.f;
        #pragma unroll
        for (int j = 0; j < NR; ++j) {
            m0 += r0[j] * wr0[j]; m1 += r0[j] * wr1[j];
            n0 += r1[j] * wr0[j]; n1 += r1[j] * wr1[j];
        }
        ax += m0 * xv0.x + n0 * xv1.x;
        ay += m1 * xv0.y + n1 * xv1.y;
    }
    if (p < end) {
        const int e0 = elist[p];
        const float2 xv0 = *(const float2*)(x + (size_t)e0 * H + lane * 2);
        const float* r0 = rbf + (size_t)e0 * NR;
        float m0 = 0.f, m1 = 0.f;
        #pragma unroll
        for (int j = 0; j < NR; ++j) { m0 += r0[j] * wr0[j]; m1 += r0[j] * wr1[j]; }
        ax += m0 * xv0.x;
        ay += m1 * xv0.y;
    }
    *(float2*)(h + (size_t)node * H + lane * 2) = make_float2(ax, ay);
}

// ---------------------------------------------------------------- MLP stack
// 128x128 block tile, 16x16 thread grid, 8x8 accumulator per thread.
__device__ __forceinline__ void stage_W(const float* __restrict__ Wg, float* Wl, int t) {
    // global row-major W[c][k] -> LDS Wl[k*LDW + c]
    for (int i = t; i < H * H; i += 256) {
        int c = i >> 7, k = i & 127;
        Wl[k * LDW + c] = Wg[i];
    }
}

__device__ __forceinline__ void layer_compute(const float* Wl, const float* hl,
        const float* __restrict__ bg, float (&acc)[8][8], int R0, int C0)
{
    #pragma unroll
    for (int j = 0; j < 8; ++j) {
        float b = bg ? bg[C0 + j] : 0.f;
        #pragma unroll
        for (int r = 0; r < 8; ++r) acc[r][j] = b;
    }
    #pragma unroll 2
    for (int k = 0; k < H; ++k) {
        const float4 h0 = *(const float4*)&hl[k * LDW + R0];
        const float4 h1 = *(const float4*)&hl[k * LDW + R0 + 4];
        const float4 w0 = *(const float4*)&Wl[k * LDW + C0];
        const float4 w1 = *(const float4*)&Wl[k * LDW + C0 + 4];
        const float hr[8] = {h0.x, h0.y, h0.z, h0.w, h1.x, h1.y, h1.z, h1.w};
        const float wv[8] = {w0.x, w0.y, w0.z, w0.w, w1.x, w1.y, w1.z, w1.w};
        #pragma unroll
        for (int r = 0; r < 8; ++r)
            #pragma unroll
            for (int j = 0; j < 8; ++j)
                acc[r][j] += hr[r] * wv[j];
    }
}

__device__ __forceinline__ void writeback_silu(float* hl, float (&acc)[8][8], int R0, int C0) {
    #pragma unroll
    for (int j = 0; j < 8; ++j) {
        const int c = C0 + j;
        *(float4*)&hl[c * LDW + R0] =
            make_float4(silu_f(acc[0][j]), silu_f(acc[1][j]), silu_f(acc[2][j]), silu_f(acc[3][j]));
        *(float4*)&hl[c * LDW + R0 + 4] =
            make_float4(silu_f(acc[4][j]), silu_f(acc[5][j]), silu_f(acc[6][j]), silu_f(acc[7][j]));
    }
}

__global__ __launch_bounds__(256, 1) void mlp4(
    const float* __restrict__ hg,
    const float* __restrict__ W1, const float* __restrict__ b1,
    const float* __restrict__ W2, const float* __restrict__ b2,
    const float* __restrict__ W3, const float* __restrict__ b3,
    const float* __restrict__ Wo,
    float* __restrict__ out, int N)
{
    __shared__ float hl[H * LDW];   // [k][r] 67.5 KB
    __shared__ float Wl[H * LDW];   // [k][c] 67.5 KB
    const int t = threadIdx.x;
    const int R0 = (t >> 4) * 8;    // 8 rows per thread
    const int C0 = (t & 15) * 8;    // 8 cols per thread
    const int row0 = blockIdx.x * MT;

    // stage h tile transposed (coalesced global read)
    for (int i = t; i < MT * H; i += 256) {
        int r = i >> 7, k = i & 127;
        int row = row0 + r;
        hl[k * LDW + r] = (row < N) ? hg[(size_t)row * H + k] : 0.f;
    }
    stage_W(W1, Wl, t);
    __syncthreads();

    float acc[8][8];
    layer_compute(Wl, hl, b1, acc, R0, C0);
    __syncthreads();
    writeback_silu(hl, acc, R0, C0);
    stage_W(W2, Wl, t);
    __syncthreads();

    layer_compute(Wl, hl, b2, acc, R0, C0);
    __syncthreads();
    writeback_silu(hl, acc, R0, C0);
    stage_W(W3, Wl, t);
    __syncthreads();

    layer_compute(Wl, hl, b3, acc, R0, C0);
    __syncthreads();
    writeback_silu(hl, acc, R0, C0);
    stage_W(Wo, Wl, t);
    __syncthreads();

    layer_compute(Wl, hl, nullptr, acc, R0, C0);

    #pragma unroll
    for (int r = 0; r < 8; ++r) {
        const int row = row0 + R0 + r;
        if (row < N) {
            float4* op = (float4*)(out + (size_t)row * H + C0);
            op[0] = make_float4(acc[r][0], acc[r][1], acc[r][2], acc[r][3]);
            op[1] = make_float4(acc[r][4], acc[r][5], acc[r][6], acc[r][7]);
        }
    }
}

// ---------------------------------------------------------------- launch
static inline size_t align256(size_t v) { return (v + 255) & ~(size_t)255; }

extern "C" void kernel_launch(void* const* d_in, const int* in_sizes, int n_in,
                              void* d_out, int out_size, void* d_ws, size_t ws_size,
                              hipStream_t stream) {
    const float* x     = (const float*)d_in[0];
    const float* rbf   = (const float*)d_in[1];
    const int*   idx   = (const int*)d_in[2];
    const float* W_rbf = (const float*)d_in[4];
    const float* W1    = (const float*)d_in[5];
    const float* b1    = (const float*)d_in[6];
    const float* W2    = (const float*)d_in[7];
    const float* b2    = (const float*)d_in[8];
    const float* W3    = (const float*)d_in[9];
    const float* b3    = (const float*)d_in[10];
    const float* Wo    = (const float*)d_in[11];
    float* out = (float*)d_out;

    const int E = in_sizes[0] / H;
    const int N = out_size / H;

    // workspace layout
    char* ws = (char*)d_ws;
    size_t off = 0;
    float* h       = (float*)(ws + off); off = align256(off + (size_t)N * H * 4);
    int*   counts  = (int*)(ws + off);   off = align256(off + (size_t)N * 4);
    int*   cursor  = (int*)(ws + off);   off = align256(off + (size_t)N * 4);
    int*   offsets = (int*)(ws + off);   off = align256(off + (size_t)(N + 1) * 4);
    int*   elist   = (int*)(ws + off);   off = align256(off + (size_t)E * 4);

    // zero counts + cursor (adjacent regions)
    hipMemsetAsync(counts, 0, (char*)offsets - (char*)counts, stream);

    hist_k<<<(E + 255) / 256, 256, 0, stream>>>(idx, counts, E);
    scan_k<<<1, 1024, 0, stream>>>(counts, offsets, N);
    fill_k<<<(E + 255) / 256, 256, 0, stream>>>(idx, offsets, cursor, elist, E);
    gather_k<<<(N + 3) / 4, 256, 0, stream>>>(x, rbf, W_rbf, offsets, elist, h, N);
    mlp4<<<(N + MT - 1) / MT, 256, 0, stream>>>(h, W1, b1, W2, b2, W3, b3, Wo, out, N);
}

// Round 3
// 889.415 us; speedup vs baseline: 2.2425x; 1.0813x over previous
//
#include <hip/hip_runtime.h>
#include <hip/hip_bf16.h>

#define H 128
#define NR 6
#define MT 128          // MLP rows per block
#define HS 136          // padded k-stride (shorts) for LDS bf16 tiles

typedef __attribute__((ext_vector_type(8))) short short8_t;
typedef __attribute__((ext_vector_type(4))) float f32x4;

__device__ __forceinline__ float silu_f(float v) {
    return v / (1.0f + __expf(-v));
}

// ----- bf16 split helpers (RNE, finite inputs only) -----
__device__ __forceinline__ unsigned short bf16_rne(float f) {
    unsigned u = __float_as_uint(f);
    u += 0x7FFF + ((u >> 16) & 1);
    return (unsigned short)(u >> 16);
}
__device__ __forceinline__ float bf16_to_f(unsigned short s) {
    return __uint_as_float(((unsigned)s) << 16);
}

// ------------------------------------------------------------ histogram
__global__ __launch_bounds__(256) void hist_k(const int* __restrict__ idx,
                                              int* __restrict__ counts, int E) {
    int i = blockIdx.x * 256 + threadIdx.x;
    if (i < E) atomicAdd(&counts[idx[i]], 1);
}

// ------------------------------------------------- single-block chunked scan
__global__ __launch_bounds__(1024) void scan_k(const int* __restrict__ counts,
                                               int* __restrict__ offsets, int N) {
    __shared__ int tmp[1024];
    const int tid = threadIdx.x;
    const int CHUNK = (N + 1023) >> 10;
    const int base = tid * CHUNK;
    int s = 0;
    for (int k = 0; k < CHUNK; ++k) {
        int j = base + k;
        if (j < N) s += counts[j];
    }
    tmp[tid] = s;
    __syncthreads();
    for (int off = 1; off < 1024; off <<= 1) {
        int v = (tid >= off) ? tmp[tid - off] : 0;
        __syncthreads();
        tmp[tid] += v;
        __syncthreads();
    }
    int run = tmp[tid] - s;
    for (int k = 0; k < CHUNK; ++k) {
        int j = base + k;
        if (j < N) { offsets[j] = run; run += counts[j]; }
    }
    if (tid == 1023) offsets[N] = run;
}

// ------------------------------------------------------------ CSR fill
__global__ __launch_bounds__(256) void fill_k(const int* __restrict__ idx,
                                              const int* __restrict__ offsets,
                                              int* __restrict__ cursor,
                                              int* __restrict__ elist, int E) {
    int i = blockIdx.x * 256 + threadIdx.x;
    if (i < E) {
        int node = idx[i];
        int pos = atomicAdd(&cursor[node], 1);
        elist[offsets[node] + pos] = i;
    }
}

// ---------------------------------------------- gather: one wave per node
__global__ __launch_bounds__(256) void gather_k(
    const float* __restrict__ x, const float* __restrict__ rbf,
    const float* __restrict__ W_rbf,
    const int* __restrict__ offsets, const int* __restrict__ elist,
    float* __restrict__ h, int N)
{
    const int t = threadIdx.x;
    const int lane = t & 63;
    const int node = blockIdx.x * 4 + (t >> 6);
    if (node >= N) return;

    const float4* wp = (const float4*)(W_rbf + lane * 12);
    const float4 wa = wp[0], wb = wp[1], wc = wp[2];
    const float wr0[NR] = {wa.x, wa.y, wa.z, wa.w, wb.x, wb.y};
    const float wr1[NR] = {wb.z, wb.w, wc.x, wc.y, wc.z, wc.w};

    const int beg = offsets[node], end = offsets[node + 1];
    float ax = 0.f, ay = 0.f;

    int p = beg;
    for (; p + 1 < end; p += 2) {
        const int e0 = elist[p], e1 = elist[p + 1];
        const float2 xv0 = *(const float2*)(x + (size_t)e0 * H + lane * 2);
        const float2 xv1 = *(const float2*)(x + (size_t)e1 * H + lane * 2);
        const float* r0 = rbf + (size_t)e0 * NR;
        const float* r1 = rbf + (size_t)e1 * NR;
        float m0 = 0.f, m1 = 0.f, n0 = 0.f, n1 = 0.f;
        #pragma unroll
        for (int j = 0; j < NR; ++j) {
            m0 += r0[j] * wr0[j]; m1 += r0[j] * wr1[j];
            n0 += r1[j] * wr0[j]; n1 += r1[j] * wr1[j];
        }
        ax += m0 * xv0.x + n0 * xv1.x;
        ay += m1 * xv0.y + n1 * xv1.y;
    }
    if (p < end) {
        const int e0 = elist[p];
        const float2 xv0 = *(const float2*)(x + (size_t)e0 * H + lane * 2);
        const float* r0 = rbf + (size_t)e0 * NR;
        float m0 = 0.f, m1 = 0.f;
        #pragma unroll
        for (int j = 0; j < NR; ++j) { m0 += r0[j] * wr0[j]; m1 += r0[j] * wr1[j]; }
        ax += m0 * xv0.x;
        ay += m1 * xv0.y;
    }
    *(float2*)(h + (size_t)node * H + lane * 2) = make_float2(ax, ay);
}

// =================================================================== MLP
// Split-bf16 MFMA: v = hi + lo (bf16 each); y = h@W.T via hi*Whi + hi*Wlo + lo*Whi.
// 16x16x32 bf16 MFMA. A-frag: A[m=lane&15][k=quad*8+j]; B-frag: W[c=lane&15][k=quad*8+j]
// (both row-major contiguous 16B); D: col=lane&15, row=quad*4+reg  [m89/m91-verified].

__device__ __forceinline__ void stage_w_lds(const float* __restrict__ Wg,
        unsigned short* w_hi, unsigned short* w_lo, int t)
{
    for (int i = t * 4; i < H * H; i += 1024) {
        const float4 v = *(const float4*)(Wg + i);
        const int c = i >> 7, k = i & 127;
        ushort4 hi4, lo4;
        hi4.x = bf16_rne(v.x); lo4.x = bf16_rne(v.x - bf16_to_f(hi4.x));
        hi4.y = bf16_rne(v.y); lo4.y = bf16_rne(v.y - bf16_to_f(hi4.y));
        hi4.z = bf16_rne(v.z); lo4.z = bf16_rne(v.z - bf16_to_f(hi4.z));
        hi4.w = bf16_rne(v.w); lo4.w = bf16_rne(v.w - bf16_to_f(hi4.w));
        *(ushort4*)&w_hi[c * HS + k] = hi4;
        *(ushort4*)&w_lo[c * HS + k] = lo4;
    }
}

__device__ __forceinline__ void compute_gemm(
    const unsigned short* h_hi, const unsigned short* h_lo,
    const unsigned short* w_hi, const unsigned short* w_lo,
    const float* bl, int wv, int lr, int quad, f32x4 (&acc)[2][8])
{
    short8_t a_hi[2][4], a_lo[2][4];
    #pragma unroll
    for (int s = 0; s < 2; ++s) {
        const int row = (wv * 2 + s) * 16 + lr;
        #pragma unroll
        for (int kb = 0; kb < 4; ++kb) {
            const int off = row * HS + kb * 32 + quad * 8;
            a_hi[s][kb] = *(const short8_t*)&h_hi[off];
            a_lo[s][kb] = *(const short8_t*)&h_lo[off];
        }
    }
    #pragma unroll 2
    for (int ct = 0; ct < 8; ++ct) {
        const int c = ct * 16 + lr;
        const float b = bl[c];
        f32x4 acc0 = {b, b, b, b}, acc1 = {b, b, b, b};
        short8_t b_hi[4], b_lo[4];
        #pragma unroll
        for (int kb = 0; kb < 4; ++kb) {
            const int off = c * HS + kb * 32 + quad * 8;
            b_hi[kb] = *(const short8_t*)&w_hi[off];
            b_lo[kb] = *(const short8_t*)&w_lo[off];
        }
        #pragma unroll
        for (int kb = 0; kb < 4; ++kb) {
            acc0 = __builtin_amdgcn_mfma_f32_16x16x32_bf16(a_hi[0][kb], b_hi[kb], acc0, 0, 0, 0);
            acc1 = __builtin_amdgcn_mfma_f32_16x16x32_bf16(a_hi[1][kb], b_hi[kb], acc1, 0, 0, 0);
            acc0 = __builtin_amdgcn_mfma_f32_16x16x32_bf16(a_hi[0][kb], b_lo[kb], acc0, 0, 0, 0);
            acc1 = __builtin_amdgcn_mfma_f32_16x16x32_bf16(a_hi[1][kb], b_lo[kb], acc1, 0, 0, 0);
            acc0 = __builtin_amdgcn_mfma_f32_16x16x32_bf16(a_lo[0][kb], b_hi[kb], acc0, 0, 0, 0);
            acc1 = __builtin_amdgcn_mfma_f32_16x16x32_bf16(a_lo[1][kb], b_hi[kb], acc1, 0, 0, 0);
        }
        acc[0][ct] = acc0;
        acc[1][ct] = acc1;
    }
}

__device__ __forceinline__ void epilogue_silu(
    unsigned short* h_hi, unsigned short* h_lo,
    f32x4 (&acc)[2][8], int wv, int lr, int quad)
{
    #pragma unroll
    for (int s = 0; s < 2; ++s)
        #pragma unroll
        for (int ct = 0; ct < 8; ++ct)
            #pragma unroll
            for (int r = 0; r < 4; ++r) {
                const int row = (wv * 2 + s) * 16 + quad * 4 + r;
                const int col = ct * 16 + lr;
                const float v = silu_f(acc[s][ct][r]);
                const unsigned short hi = bf16_rne(v);
                h_hi[row * HS + col] = hi;
                h_lo[row * HS + col] = bf16_rne(v - bf16_to_f(hi));
            }
}

__global__ __launch_bounds__(256, 1) void mlp_mfma(
    const float* __restrict__ hg,
    const float* __restrict__ W1, const float* __restrict__ b1,
    const float* __restrict__ W2, const float* __restrict__ b2,
    const float* __restrict__ W3, const float* __restrict__ b3,
    const float* __restrict__ Wo,
    float* __restrict__ out, int N)
{
    __shared__ unsigned short h_hi[H * HS], h_lo[H * HS];   // 34 KB each
    __shared__ unsigned short w_hi[H * HS], w_lo[H * HS];   // 34 KB each
    __shared__ float bl[H];

    const int t = threadIdx.x;
    const int lane = t & 63;
    const int wv = t >> 6;
    const int lr = lane & 15;
    const int quad = lane >> 4;
    const int row0 = blockIdx.x * MT;

    // stage h tile (fp32 global, coalesced) -> split bf16 hi/lo in LDS
    for (int i = t * 4; i < MT * H; i += 1024) {
        const int r = i >> 7, k = i & 127;
        const int row = row0 + r;
        const float4 v = (row < N) ? *(const float4*)(hg + (size_t)row * H + k)
                                   : make_float4(0.f, 0.f, 0.f, 0.f);
        ushort4 hi4, lo4;
        hi4.x = bf16_rne(v.x); lo4.x = bf16_rne(v.x - bf16_to_f(hi4.x));
        hi4.y = bf16_rne(v.y); lo4.y = bf16_rne(v.y - bf16_to_f(hi4.y));
        hi4.z = bf16_rne(v.z); lo4.z = bf16_rne(v.z - bf16_to_f(hi4.z));
        hi4.w = bf16_rne(v.w); lo4.w = bf16_rne(v.w - bf16_to_f(hi4.w));
        *(ushort4*)&h_hi[r * HS + k] = hi4;
        *(ushort4*)&h_lo[r * HS + k] = lo4;
    }
    stage_w_lds(W1, w_hi, w_lo, t);
    if (t < H) bl[t] = b1[t];
    __syncthreads();

    f32x4 acc[2][8];

    // layer 1
    compute_gemm(h_hi, h_lo, w_hi, w_lo, bl, wv, lr, quad, acc);
    __syncthreads();
    epilogue_silu(h_hi, h_lo, acc, wv, lr, quad);
    stage_w_lds(W2, w_hi, w_lo, t);
    if (t < H) bl[t] = b2[t];
    __syncthreads();

    // layer 2
    compute_gemm(h_hi, h_lo, w_hi, w_lo, bl, wv, lr, quad, acc);
    __syncthreads();
    epilogue_silu(h_hi, h_lo, acc, wv, lr, quad);
    stage_w_lds(W3, w_hi, w_lo, t);
    if (t < H) bl[t] = b3[t];
    __syncthreads();

    // layer 3
    compute_gemm(h_hi, h_lo, w_hi, w_lo, bl, wv, lr, quad, acc);
    __syncthreads();
    epilogue_silu(h_hi, h_lo, acc, wv, lr, quad);
    stage_w_lds(Wo, w_hi, w_lo, t);
    if (t < H) bl[t] = 0.f;
    __syncthreads();

    // output layer (no bias, no silu) -> global fp32
    compute_gemm(h_hi, h_lo, w_hi, w_lo, bl, wv, lr, quad, acc);

    #pragma unroll
    for (int s = 0; s < 2; ++s)
        #pragma unroll
        for (int ct = 0; ct < 8; ++ct)
            #pragma unroll
            for (int r = 0; r < 4; ++r) {
                const int row = row0 + (wv * 2 + s) * 16 + quad * 4 + r;
                if (row < N) out[(size_t)row * H + ct * 16 + lr] = acc[s][ct][r];
            }
}

// ---------------------------------------------------------------- launch
static inline size_t align256(size_t v) { return (v + 255) & ~(size_t)255; }

extern "C" void kernel_launch(void* const* d_in, const int* in_sizes, int n_in,
                              void* d_out, int out_size, void* d_ws, size_t ws_size,
                              hipStream_t stream) {
    const float* x     = (const float*)d_in[0];
    const float* rbf   = (const float*)d_in[1];
    const int*   idx   = (const int*)d_in[2];
    const float* W_rbf = (const float*)d_in[4];
    const float* W1    = (const float*)d_in[5];
    const float* b1    = (const float*)d_in[6];
    const float* W2    = (const float*)d_in[7];
    const float* b2    = (const float*)d_in[8];
    const float* W3    = (const float*)d_in[9];
    const float* b3    = (const float*)d_in[10];
    const float* Wo    = (const float*)d_in[11];
    float* out = (float*)d_out;

    const int E = in_sizes[0] / H;
    const int N = out_size / H;

    char* ws = (char*)d_ws;
    size_t off = 0;
    float* h       = (float*)(ws + off); off = align256(off + (size_t)N * H * 4);
    int*   counts  = (int*)(ws + off);   off = align256(off + (size_t)N * 4);
    int*   cursor  = (int*)(ws + off);   off = align256(off + (size_t)N * 4);
    int*   offsets = (int*)(ws + off);   off = align256(off + (size_t)(N + 1) * 4);
    int*   elist   = (int*)(ws + off);   off = align256(off + (size_t)E * 4);

    hipMemsetAsync(counts, 0, (char*)offsets - (char*)counts, stream);

    hist_k<<<(E + 255) / 256, 256, 0, stream>>>(idx, counts, E);
    scan_k<<<1, 1024, 0, stream>>>(counts, offsets, N);
    fill_k<<<(E + 255) / 256, 256, 0, stream>>>(idx, offsets, cursor, elist, E);
    gather_k<<<(N + 3) / 4, 256, 0, stream>>>(x, rbf, W_rbf, offsets, elist, h, N);
    mlp_mfma<<<(N + MT - 1) / MT, 256, 0, stream>>>(h, W1, b1, W2, b2, W3, b3, Wo, out, N);
}

// Round 4
// 791.319 us; speedup vs baseline: 2.5204x; 1.1240x over previous
//
#include <hip/hip_runtime.h>
#include <hip/hip_bf16.h>

#define H 128
#define NR 6
#define MT 128          // MLP rows per block
#define HS 136          // padded k-stride (shorts) for LDS bf16 tiles

typedef __attribute__((ext_vector_type(8))) short short8_t;
typedef __attribute__((ext_vector_type(4))) float f32x4;

__device__ __forceinline__ float silu_f(float v) {
    return v / (1.0f + __expf(-v));
}

// ----- bf16 split helpers (RNE, finite inputs only) -----
__device__ __forceinline__ unsigned short bf16_rne(float f) {
    unsigned u = __float_as_uint(f);
    u += 0x7FFF + ((u >> 16) & 1);
    return (unsigned short)(u >> 16);
}
__device__ __forceinline__ float bf16_to_f(unsigned short s) {
    return __uint_as_float(((unsigned)s) << 16);
}

// ------------------------------------------------------------ histogram
__global__ __launch_bounds__(256) void hist_k(const int* __restrict__ idx,
                                              int* __restrict__ counts, int E) {
    int i = blockIdx.x * 256 + threadIdx.x;
    if (i < E) atomicAdd(&counts[idx[i]], 1);
}

// ---------------------------------------- coalesced single-block scan
__global__ __launch_bounds__(1024) void scan_k(const int* __restrict__ counts,
                                               int* __restrict__ offsets, int N) {
    __shared__ int wsum[16];
    __shared__ int runv;
    const int tid = threadIdx.x, lane = tid & 63, wv = tid >> 6;
    if (tid == 0) runv = 0;
    __syncthreads();
    for (int base = 0; base < N; base += 1024) {
        const int j = base + tid;
        const int v_in = (j < N) ? counts[j] : 0;
        int v = v_in;
        #pragma unroll
        for (int d = 1; d < 64; d <<= 1) {
            int u = __shfl_up(v, d);
            if (lane >= d) v += u;
        }
        if (lane == 63) wsum[wv] = v;
        __syncthreads();
        if (tid < 16) {
            int s = wsum[tid];
            #pragma unroll
            for (int d = 1; d < 16; d <<= 1) {
                int u = __shfl_up(s, d);
                if (tid >= d) s += u;
            }
            wsum[tid] = s;
        }
        __syncthreads();
        const int wexcl = (wv == 0) ? 0 : wsum[wv - 1];
        const int r0 = runv;
        if (j < N) offsets[j] = r0 + wexcl + (v - v_in);
        const int tot = wsum[15];
        __syncthreads();               // all reads of runv/wsum done
        if (tid == 0) runv = r0 + tot;
        __syncthreads();               // update visible before next tile
    }
    if (tid == 0) offsets[N] = runv;
}

// ------------------------------------------------------------ CSR fill
__global__ __launch_bounds__(256) void fill_k(const int* __restrict__ idx,
                                              const int* __restrict__ offsets,
                                              int* __restrict__ cursor,
                                              int* __restrict__ elist, int E) {
    int i = blockIdx.x * 256 + threadIdx.x;
    if (i < E) {
        int node = idx[i];
        int pos = atomicAdd(&cursor[node], 1);
        elist[offsets[node] + pos] = i;
    }
}

// ---------------------------------------------- gather: one wave per node
// Edge ids for the node fetched in ONE coalesced lane-load, broadcast by shfl;
// 4 edges of x+rbf loads issued per iteration to break the latency chain.
__global__ __launch_bounds__(256) void gather_k(
    const float* __restrict__ x, const float* __restrict__ rbf,
    const float* __restrict__ W_rbf,
    const int* __restrict__ offsets, const int* __restrict__ elist,
    float* __restrict__ h, int N)
{
    const int t = threadIdx.x;
    const int lane = t & 63;
    const int node = blockIdx.x * 4 + (t >> 6);
    if (node >= N) return;

    // W_rbf rows for this lane's two columns (12 consecutive floats)
    const float4* wp = (const float4*)(W_rbf + lane * 12);
    const float4 wa = wp[0], wb = wp[1], wc = wp[2];
    const float wr0[NR] = {wa.x, wa.y, wa.z, wa.w, wb.x, wb.y};
    const float wr1[NR] = {wb.z, wb.w, wc.x, wc.y, wc.z, wc.w};

    const int beg = offsets[node], end = offsets[node + 1];
    float ax = 0.f, ay = 0.f;

    for (int base = beg; base < end; base += 64) {
        const int cnt = min(64, end - base);
        const int e_lane = (lane < cnt) ? elist[base + lane] : 0;
        int p = 0;
        for (; p + 4 <= cnt; p += 4) {
            int ev[4];
            float2 xv[4];
            float2 rv[4][3];
            #pragma unroll
            for (int q = 0; q < 4; ++q) ev[q] = __shfl(e_lane, p + q);
            #pragma unroll
            for (int q = 0; q < 4; ++q) {
                const size_t e = (size_t)ev[q];
                xv[q] = *(const float2*)(x + e * H + lane * 2);
                const float2* rp = (const float2*)(rbf + e * NR);
                rv[q][0] = rp[0]; rv[q][1] = rp[1]; rv[q][2] = rp[2];
            }
            #pragma unroll
            for (int q = 0; q < 4; ++q) {
                const float rr[NR] = {rv[q][0].x, rv[q][0].y, rv[q][1].x,
                                      rv[q][1].y, rv[q][2].x, rv[q][2].y};
                float m0 = 0.f, m1 = 0.f;
                #pragma unroll
                for (int j = 0; j < NR; ++j) { m0 += rr[j] * wr0[j]; m1 += rr[j] * wr1[j]; }
                ax += m0 * xv[q].x;
                ay += m1 * xv[q].y;
            }
        }
        for (; p < cnt; ++p) {
            const size_t e = (size_t)__shfl(e_lane, p);
            const float2 xv0 = *(const float2*)(x + e * H + lane * 2);
            const float2* rp = (const float2*)(rbf + e * NR);
            const float2 ra = rp[0], rb2 = rp[1], rc2 = rp[2];
            const float rr[NR] = {ra.x, ra.y, rb2.x, rb2.y, rc2.x, rc2.y};
            float m0 = 0.f, m1 = 0.f;
            #pragma unroll
            for (int j = 0; j < NR; ++j) { m0 += rr[j] * wr0[j]; m1 += rr[j] * wr1[j]; }
            ax += m0 * xv0.x;
            ay += m1 * xv0.y;
        }
    }
    *(float2*)(h + (size_t)node * H + lane * 2) = make_float2(ax, ay);
}

// =================================================================== MLP
// Split-bf16 MFMA (hi*Whi + hi*Wlo + lo*Whi), 16x16x32 bf16.
// 512 threads = 8 waves; wave wv owns 16-row block wv. 2 waves/SIMD.
// A-frag: A[m=lane&15][k=quad*8+j]; B-frag: W[c=lane&15][k=quad*8+j];
// D: col=lane&15, row=quad*4+reg  [m89/m91-verified].

__device__ __forceinline__ void stage_w_lds(const float* __restrict__ Wg,
        unsigned short* w_hi, unsigned short* w_lo, int t)
{
    for (int i = t * 4; i < H * H; i += 2048) {
        const float4 v = *(const float4*)(Wg + i);
        const int c = i >> 7, k = i & 127;
        ushort4 hi4, lo4;
        hi4.x = bf16_rne(v.x); lo4.x = bf16_rne(v.x - bf16_to_f(hi4.x));
        hi4.y = bf16_rne(v.y); lo4.y = bf16_rne(v.y - bf16_to_f(hi4.y));
        hi4.z = bf16_rne(v.z); lo4.z = bf16_rne(v.z - bf16_to_f(hi4.z));
        hi4.w = bf16_rne(v.w); lo4.w = bf16_rne(v.w - bf16_to_f(hi4.w));
        *(ushort4*)&w_hi[c * HS + k] = hi4;
        *(ushort4*)&w_lo[c * HS + k] = lo4;
    }
}

__device__ __forceinline__ void compute_gemm(
    const unsigned short* h_hi, const unsigned short* h_lo,
    const unsigned short* w_hi, const unsigned short* w_lo,
    const float* bl, int wv, int lr, int quad, f32x4 (&acc)[8])
{
    short8_t a_hi[4], a_lo[4];
    const int row = wv * 16 + lr;
    #pragma unroll
    for (int kb = 0; kb < 4; ++kb) {
        const int off = row * HS + kb * 32 + quad * 8;
        a_hi[kb] = *(const short8_t*)&h_hi[off];
        a_lo[kb] = *(const short8_t*)&h_lo[off];
    }
    #pragma unroll
    for (int ct = 0; ct < 8; ct += 2) {
        const int c0 = ct * 16 + lr, c1 = (ct + 1) * 16 + lr;
        const float bb0 = bl[c0], bb1 = bl[c1];
        f32x4 A0 = {bb0, bb0, bb0, bb0}, A1 = {bb1, bb1, bb1, bb1};
        short8_t b0h[4], b0l[4], b1h[4], b1l[4];
        #pragma unroll
        for (int kb = 0; kb < 4; ++kb) {
            const int o0 = c0 * HS + kb * 32 + quad * 8;
            const int o1 = c1 * HS + kb * 32 + quad * 8;
            b0h[kb] = *(const short8_t*)&w_hi[o0];
            b0l[kb] = *(const short8_t*)&w_lo[o0];
            b1h[kb] = *(const short8_t*)&w_hi[o1];
            b1l[kb] = *(const short8_t*)&w_lo[o1];
        }
        #pragma unroll
        for (int kb = 0; kb < 4; ++kb) {
            A0 = __builtin_amdgcn_mfma_f32_16x16x32_bf16(a_hi[kb], b0h[kb], A0, 0, 0, 0);
            A1 = __builtin_amdgcn_mfma_f32_16x16x32_bf16(a_hi[kb], b1h[kb], A1, 0, 0, 0);
            A0 = __builtin_amdgcn_mfma_f32_16x16x32_bf16(a_hi[kb], b0l[kb], A0, 0, 0, 0);
            A1 = __builtin_amdgcn_mfma_f32_16x16x32_bf16(a_hi[kb], b1l[kb], A1, 0, 0, 0);
            A0 = __builtin_amdgcn_mfma_f32_16x16x32_bf16(a_lo[kb], b0h[kb], A0, 0, 0, 0);
            A1 = __builtin_amdgcn_mfma_f32_16x16x32_bf16(a_lo[kb], b1h[kb], A1, 0, 0, 0);
        }
        acc[ct] = A0;
        acc[ct + 1] = A1;
    }
}

__device__ __forceinline__ void epilogue_silu(
    unsigned short* h_hi, unsigned short* h_lo,
    f32x4 (&acc)[8], int wv, int lr, int quad)
{
    #pragma unroll
    for (int ct = 0; ct < 8; ++ct)
        #pragma unroll
        for (int r = 0; r < 4; ++r) {
            const int row = wv * 16 + quad * 4 + r;
            const int col = ct * 16 + lr;
            const float v = silu_f(acc[ct][r]);
            const unsigned short hi = bf16_rne(v);
            h_hi[row * HS + col] = hi;
            h_lo[row * HS + col] = bf16_rne(v - bf16_to_f(hi));
        }
}

__global__ __launch_bounds__(512, 2) void mlp_mfma(
    const float* __restrict__ hg,
    const float* __restrict__ W1, const float* __restrict__ b1,
    const float* __restrict__ W2, const float* __restrict__ b2,
    const float* __restrict__ W3, const float* __restrict__ b3,
    const float* __restrict__ Wo,
    float* __restrict__ out, int N)
{
    __shared__ unsigned short h_hi[H * HS], h_lo[H * HS];   // 34 KB each
    __shared__ unsigned short w_hi[H * HS], w_lo[H * HS];   // 34 KB each
    __shared__ float bl[H];

    const int t = threadIdx.x;
    const int lane = t & 63;
    const int wv = t >> 6;          // 0..7: 16-row block
    const int lr = lane & 15;
    const int quad = lane >> 4;
    const int row0 = blockIdx.x * MT;

    // stage h tile (fp32 global, coalesced) -> split bf16 hi/lo in LDS
    for (int i = t * 4; i < MT * H; i += 2048) {
        const int r = i >> 7, k = i & 127;
        const int row = row0 + r;
        const float4 v = (row < N) ? *(const float4*)(hg + (size_t)row * H + k)
                                   : make_float4(0.f, 0.f, 0.f, 0.f);
        ushort4 hi4, lo4;
        hi4.x = bf16_rne(v.x); lo4.x = bf16_rne(v.x - bf16_to_f(hi4.x));
        hi4.y = bf16_rne(v.y); lo4.y = bf16_rne(v.y - bf16_to_f(hi4.y));
        hi4.z = bf16_rne(v.z); lo4.z = bf16_rne(v.z - bf16_to_f(hi4.z));
        hi4.w = bf16_rne(v.w); lo4.w = bf16_rne(v.w - bf16_to_f(hi4.w));
        *(ushort4*)&h_hi[r * HS + k] = hi4;
        *(ushort4*)&h_lo[r * HS + k] = lo4;
    }
    stage_w_lds(W1, w_hi, w_lo, t);
    if (t < H) bl[t] = b1[t];
    __syncthreads();

    f32x4 acc[8];

    compute_gemm(h_hi, h_lo, w_hi, w_lo, bl, wv, lr, quad, acc);
    __syncthreads();
    epilogue_silu(h_hi, h_lo, acc, wv, lr, quad);
    stage_w_lds(W2, w_hi, w_lo, t);
    if (t < H) bl[t] = b2[t];
    __syncthreads();

    compute_gemm(h_hi, h_lo, w_hi, w_lo, bl, wv, lr, quad, acc);
    __syncthreads();
    epilogue_silu(h_hi, h_lo, acc, wv, lr, quad);
    stage_w_lds(W3, w_hi, w_lo, t);
    if (t < H) bl[t] = b3[t];
    __syncthreads();

    compute_gemm(h_hi, h_lo, w_hi, w_lo, bl, wv, lr, quad, acc);
    __syncthreads();
    epilogue_silu(h_hi, h_lo, acc, wv, lr, quad);
    stage_w_lds(Wo, w_hi, w_lo, t);
    if (t < H) bl[t] = 0.f;
    __syncthreads();

    compute_gemm(h_hi, h_lo, w_hi, w_lo, bl, wv, lr, quad, acc);

    #pragma unroll
    for (int ct = 0; ct < 8; ++ct)
        #pragma unroll
        for (int r = 0; r < 4; ++r) {
            const int row = row0 + wv * 16 + quad * 4 + r;
            if (row < N) out[(size_t)row * H + ct * 16 + lr] = acc[ct][r];
        }
}

// ---------------------------------------------------------------- launch
static inline size_t align256(size_t v) { return (v + 255) & ~(size_t)255; }

extern "C" void kernel_launch(void* const* d_in, const int* in_sizes, int n_in,
                              void* d_out, int out_size, void* d_ws, size_t ws_size,
                              hipStream_t stream) {
    const float* x     = (const float*)d_in[0];
    const float* rbf   = (const float*)d_in[1];
    const int*   idx   = (const int*)d_in[2];
    const float* W_rbf = (const float*)d_in[4];
    const float* W1    = (const float*)d_in[5];
    const float* b1    = (const float*)d_in[6];
    const float* W2    = (const float*)d_in[7];
    const float* b2    = (const float*)d_in[8];
    const float* W3    = (const float*)d_in[9];
    const float* b3    = (const float*)d_in[10];
    const float* Wo    = (const float*)d_in[11];
    float* out = (float*)d_out;

    const int E = in_sizes[0] / H;
    const int N = out_size / H;

    char* ws = (char*)d_ws;
    size_t off = 0;
    float* h       = (float*)(ws + off); off = align256(off + (size_t)N * H * 4);
    int*   counts  = (int*)(ws + off);   off = align256(off + (size_t)N * 4);
    int*   cursor  = (int*)(ws + off);   off = align256(off + (size_t)N * 4);
    int*   offsets = (int*)(ws + off);   off = align256(off + (size_t)(N + 1) * 4);
    int*   elist   = (int*)(ws + off);   off = align256(off + (size_t)E * 4);

    hipMemsetAsync(counts, 0, (char*)offsets - (char*)counts, stream);

    hist_k<<<(E + 255) / 256, 256, 0, stream>>>(idx, counts, E);
    scan_k<<<1, 1024, 0, stream>>>(counts, offsets, N);
    fill_k<<<(E + 255) / 256, 256, 0, stream>>>(idx, offsets, cursor, elist, E);
    gather_k<<<(N + 3) / 4, 256, 0, stream>>>(x, rbf, W_rbf, offsets, elist, h, N);
    mlp_mfma<<<(N + MT - 1) / MT, 512, 0, stream>>>(h, W1, b1, W2, b2, W3, b3, Wo, out, N);
}